// Round 13
// baseline (111.636 us; speedup 1.0000x reference)
//
#include <hip/hip_runtime.h>
#include <hip/hip_bf16.h>

typedef __attribute__((ext_vector_type(8))) short bf16x8;
typedef __attribute__((ext_vector_type(4))) float f32x4;
typedef __attribute__((ext_vector_type(4))) short short4v;
typedef __attribute__((ext_vector_type(4))) int int4v;
typedef unsigned short ushort_t;

#define CC 120
#define LL 469
#define HH 64

constexpr int NBATCH = 1024;           // (s,b) pairs; raw reshape => batch contiguous
constexpr int KSTEPS = (LL + 31) / 32; // 15

// ---- LDS layout ----
// phase 1: Xf[2][120][32] f32 @0 (30720 B, src-chunk-XOR swizzled, dbuf DMA),
//          Wl[8192 shorts] @30720 (16384 B, SINGLE buffer, refreshed via registers)
//          -> 47104 B; SMEM 49152 => 3 blocks/CU (r9 was 63.5K => 2)
// phase 2: Qb @0 (16 KB, [128]x128B swz), Kb @16384, Vb @32768 ([64]x256B swz)
//          Pb @0 (32 KB) aliases Q+K after QK^T barrier; epilogue Ob f32 [120][68] @0
constexpr int XBUF_FLOATS = 120 * 32;              // 3840 dwords = 15/thread
constexpr int X_BYTES     = 2 * XBUF_FLOATS * 4;   // 30720
constexpr int WB_SHORTS   = 8192;                  // 16 KB W buffer (15 live KB + pad)
constexpr int SMEM_BYTES  = 49152;                 // phase2 needs 48K
constexpr int WIMG_SHORTS = KSTEPS * WB_SHORTS;    // 122880
constexpr int WIMG_BYTES  = WIMG_SHORTS * 2;       // 245760

__device__ __forceinline__ ushort_t f2bf(float f) {
  __hip_bfloat16 h = __float2bfloat16(f);
  return __builtin_bit_cast(ushort_t, h);
}

__device__ __forceinline__ void gload_lds4(const void* g, void* l) {
  __builtin_amdgcn_global_load_lds(
      (const __attribute__((address_space(1))) unsigned int*)g,
      (__attribute__((address_space(3))) unsigned int*)l, 4, 0, 0);
}

// XOR-swizzled LDS address for phase-2 tiles
__device__ __forceinline__ char* sptr(char* base, int row, int stride, int byteoff) {
  return base + row * stride + (byteoff ^ ((row & 7) << 4));
}

// W image: per step t a 16 KB block; first 15360 B = [192 cols][40 k] bf16, rest pad.
__global__ void prep_w(const float* __restrict__ Wk, const float* __restrict__ Wq,
                       const float* __restrict__ Wv, ushort_t* __restrict__ wimg) {
  int idx = blockIdx.x * 256 + threadIdx.x; // 122880 exactly (480 blocks)
  int t = idx / WB_SHORTS;
  int r = idx % WB_SHORTS;
  int col = r / 40, kk = r % 40;
  float v = 0.f;
  if (r < 192 * 40 && kk < 32) {
    int k = t * 32 + kk;
    int wsel = col >> 6, h = col & 63;
    const float* wp = (wsel == 0) ? Wk : (wsel == 1) ? Wq : Wv;
    if (k < LL) v = wp[(size_t)k * HH + h];
  }
  wimg[idx] = f2bf(v);
}

// W(t) -> 4 named register quads (issued FIRST so consuming them leaves X in flight)
#define WLOADR(T)                                                              \
  {                                                                            \
    const char* _s = (const char*)wimg + (size_t)(T) * 16384 + tid * 16;       \
    w0 = *(const int4v*)(_s);                                                  \
    w1 = *(const int4v*)(_s + 4096);                                           \
    w2 = *(const int4v*)(_s + 8192);                                           \
    w3 = *(const int4v*)(_s + 12288);                                          \
  }
#define WWRITER()                                                              \
  {                                                                            \
    char* _d = (char*)Wl + tid * 16;                                           \
    *(int4v*)(_d) = w0;                                                        \
    *(int4v*)(_d + 4096) = w1;                                                 \
    *(int4v*)(_d + 8192) = w2;                                                 \
    *(int4v*)(_d + 12288) = w3;                                                \
  }

template <bool WIMG>
__global__ __launch_bounds__(256, 3)
void fused_regional_head(const float* __restrict__ x,
                         const float* __restrict__ Wk,
                         const float* __restrict__ Wq,
                         const float* __restrict__ Wv,
                         const ushort_t* __restrict__ wimg,
                         float* __restrict__ out) {
  __shared__ char smem[SMEM_BYTES];
  const int tid = threadIdx.x;
  const int lane = tid & 63;
  const int wv = tid >> 6;   // wave 0..3, owns rows 32*wv .. 32*wv+31
  const int lr = lane & 15;
  const int lg = lane >> 4;
  const int batch = blockIdx.x;
  const size_t xbase = (size_t)batch * CC * LL;

  float* Xf = (float*)smem;                       // [2][120][32] f32, chunk-swizzled
  ushort_t* Wl = (ushort_t*)(smem + X_BYTES);     // [8192] shorts, single buffer

  // X stage: 15 gload_lds4 per thread. LDS linear; global source chunk-XOR
  // swizzled so ds_read of logical 16B chunk s reads phys s^(row&7).
  auto stage_x = [&](int t) {
    float* dst = Xf + (t & 1) * XBUF_FLOATS;
    const int k0 = t * 32;
    const bool tail = (t == KSTEPS - 1);
#pragma unroll
    for (int i = 0; i < 15; ++i) {
      int slot = i * 4 + wv;              // 0..59, wave-uniform
      int dw = slot * 64 + lane;          // dword in [0,3840)
      int row = dw >> 5;
      int w = dw & 31;
      int lw = (((w >> 2) ^ (row & 7)) << 2) | (w & 3); // logical k-word
      int k = k0 + lw;
      if (tail) {
        if (k >= LL) dst[dw] = 0.f;       // zero invalid (lgkm, drained at barrier)
        if (k < LL) gload_lds4(x + xbase + (size_t)row * LL + k, dst + slot * 64);
      } else {
        gload_lds4(x + xbase + (size_t)row * LL + k, dst + slot * 64);
      }
    }
  };
  auto stage_w_slow = [&](int t) {
    const int k0 = t * 32;
#pragma unroll
    for (int j = 0; j < 24; ++j) {
      int idx = j * 256 + tid;
      int col = idx >> 5, kk = idx & 31;
      int k = k0 + kk;
      int wsel = col >> 6, h = col & 63;
      const float* wp = (wsel == 0) ? Wk : (wsel == 1) ? Wq : Wv;
      float v = (k < LL) ? wp[(size_t)k * HH + h] : 0.f;
      Wl[col * 40 + kk] = f2bf(v);
    }
  };

  // ---------------- phase 1: QKV = X @ [Wk|Wq|Wv] ----------------
  f32x4 acc[2][12];
#pragma unroll
  for (int m = 0; m < 2; ++m)
#pragma unroll
    for (int n = 0; n < 12; ++n) acc[m][n] = (f32x4){0.f, 0.f, 0.f, 0.f};

  const int row0 = wv * 32 + lr;      // < 120 always
  const int row1 = wv * 32 + 16 + lr; // >= 120 for wave3, lr>=8
  const bool r1ok = row1 < CC;

  auto compute = [&](int t) {
    const float* xb = Xf + (t & 1) * XBUF_FLOATS;
    f32x4 z = (f32x4){0.f, 0.f, 0.f, 0.f};
    f32x4 c00 = *(const f32x4*)(xb + row0 * 32 + (((lg * 2) ^ (row0 & 7)) << 2));
    f32x4 c01 = *(const f32x4*)(xb + row0 * 32 + (((lg * 2 + 1) ^ (row0 & 7)) << 2));
    f32x4 c10 = r1ok ? *(const f32x4*)(xb + row1 * 32 + (((lg * 2) ^ (row1 & 7)) << 2)) : z;
    f32x4 c11 = r1ok ? *(const f32x4*)(xb + row1 * 32 + (((lg * 2 + 1) ^ (row1 & 7)) << 2)) : z;
    bf16x8 a0, a1;
#pragma unroll
    for (int j = 0; j < 4; ++j) {
      a0[j] = (short)f2bf(c00[j]); a0[4 + j] = (short)f2bf(c01[j]);
      a1[j] = (short)f2bf(c10[j]); a1[4 + j] = (short)f2bf(c11[j]);
    }
#pragma unroll
    for (int n = 0; n < 12; ++n) {
      bf16x8 b = *(const bf16x8*)(Wl + (n * 16 + lr) * 40 + lg * 8);
      acc[0][n] = __builtin_amdgcn_mfma_f32_16x16x32_bf16(a0, b, acc[0][n], 0, 0, 0);
      acc[1][n] = __builtin_amdgcn_mfma_f32_16x16x32_bf16(a1, b, acc[1][n], 0, 0, 0);
    }
  };

  if constexpr (WIMG) {
    int4v w0, w1, w2, w3;
    // prologue: W(0)->regs, X(0)->DMA, write W(0), full drain
    WLOADR(0);
    stage_x(0);
    WWRITER(); // compiler waits only the 4 W loads (vmcnt(15): X stays in flight)
    asm volatile("s_waitcnt vmcnt(0) lgkmcnt(0)" ::: "memory");
    __builtin_amdgcn_s_barrier();
    __builtin_amdgcn_sched_barrier(0);
    for (int t = 0; t < KSTEPS; ++t) {
      if (t + 1 < KSTEPS) {
        WLOADR(t + 1);   // 4 loads first (oldest)
        stage_x(t + 1);  // then 15 X-DMAs
      }
      compute(t);
      asm volatile("s_waitcnt lgkmcnt(0)" ::: "memory");
      __builtin_amdgcn_sched_barrier(0);
      __builtin_amdgcn_s_barrier();       // barrier 1: all waves done reading Wl
      if (t + 1 < KSTEPS) WWRITER();      // vmcnt(15) auto: W regs ready, X in flight
      asm volatile("s_waitcnt vmcnt(0) lgkmcnt(0)" ::: "memory");
      __builtin_amdgcn_sched_barrier(0);
      __builtin_amdgcn_s_barrier();       // barrier 2: X(t+1) + W(t+1) visible
      __builtin_amdgcn_sched_barrier(0);
    }
  } else {
    // slow fallback (unused when ws present)
    stage_x(0);
    stage_w_slow(0);
    __syncthreads();
    for (int t = 0; t < KSTEPS; ++t) {
      if (t + 1 < KSTEPS) stage_x(t + 1);
      compute(t);
      __syncthreads();
      if (t + 1 < KSTEPS) {
        stage_w_slow(t + 1);
        __syncthreads();
      }
    }
  }
  __syncthreads(); // staging region dead; phase-2 tiles take over

  // ---------------- write Q,K,V (bf16, swizzled) ----------------
  char* Qb = smem;
  char* Kb = smem + 16384;
  char* Vb = smem + 32768;
  char* Pb = smem;
#pragma unroll
  for (int mt = 0; mt < 2; ++mt) {
#pragma unroll
    for (int r = 0; r < 4; ++r) {
      int row = wv * 32 + mt * 16 + lg * 4 + r;
#pragma unroll
      for (int n = 0; n < 4; ++n) {
        *(ushort_t*)sptr(Kb, row, 128, (n * 16 + lr) * 2) = f2bf(acc[mt][n][r]);
        *(ushort_t*)sptr(Qb, row, 128, (n * 16 + lr) * 2) = f2bf(acc[mt][4 + n][r]);
      }
    }
    // V^T packed: 4 consecutive d-rows -> ds_write_b64
#pragma unroll
    for (int n = 0; n < 4; ++n) {
      short4v pk;
#pragma unroll
      for (int r = 0; r < 4; ++r) pk[r] = (short)f2bf(acc[mt][8 + n][r]);
      *(short4v*)sptr(Vb, n * 16 + lr, 256, (wv * 32 + mt * 16 + lg * 4) * 2) = pk;
    }
  }
  __syncthreads();

  // ---------------- QK^T ----------------
  f32x4 accw[2][8];
#pragma unroll
  for (int m = 0; m < 2; ++m)
#pragma unroll
    for (int n = 0; n < 8; ++n) accw[m][n] = (f32x4){0.f, 0.f, 0.f, 0.f};
#pragma unroll
  for (int ks = 0; ks < 2; ++ks) {
    bf16x8 a0 = *(const bf16x8*)sptr(Qb, wv * 32 + lr, 128, ks * 64 + lg * 16);
    bf16x8 a1 = *(const bf16x8*)sptr(Qb, wv * 32 + 16 + lr, 128, ks * 64 + lg * 16);
#pragma unroll
    for (int n = 0; n < 8; ++n) {
      bf16x8 b = *(const bf16x8*)sptr(Kb, n * 16 + lr, 128, ks * 64 + lg * 16);
      accw[0][n] = __builtin_amdgcn_mfma_f32_16x16x32_bf16(a0, b, accw[0][n], 0, 0, 0);
      accw[1][n] = __builtin_amdgcn_mfma_f32_16x16x32_bf16(a1, b, accw[1][n], 0, 0, 0);
    }
  }
  __syncthreads(); // all done reading Q/K before P overwrites

  // ---------------- softmax (wave-parallel over 16-lane col groups) ----------------
#pragma unroll
  for (int mt = 0; mt < 2; ++mt)
#pragma unroll
    for (int r = 0; r < 4; ++r) {
      float l[8];
      float m = -1e30f;
#pragma unroll
      for (int n = 0; n < 8; ++n) {
        float v = accw[mt][n][r] * 0.125f;
        if (n == 7 && lr >= 8) v = -1e30f; // col = 112+lr >= 120 masked
        l[n] = v;
        m = fmaxf(m, v);
      }
#pragma unroll
      for (int off = 1; off < 16; off <<= 1) m = fmaxf(m, __shfl_xor(m, off));
      float s = 0.f;
#pragma unroll
      for (int n = 0; n < 8; ++n) {
        float p = __expf(l[n] - m);
        l[n] = p;
        s += p;
      }
#pragma unroll
      for (int off = 1; off < 16; off <<= 1) s += __shfl_xor(s, off);
      float inv = 1.f / s;
      int row = wv * 32 + mt * 16 + lg * 4 + r;
#pragma unroll
      for (int n = 0; n < 8; ++n)
        *(ushort_t*)sptr(Pb, row, 256, (n * 16 + lr) * 2) = f2bf(l[n] * inv);
    }
  // no barrier: each wave reads only its own P rows; V covered by barrier above

  // ---------------- out = P @ V ----------------
  f32x4 acco[2][4];
#pragma unroll
  for (int m = 0; m < 2; ++m)
#pragma unroll
    for (int n = 0; n < 4; ++n) acco[m][n] = (f32x4){0.f, 0.f, 0.f, 0.f};
#pragma unroll
  for (int ks = 0; ks < 4; ++ks) {
    bf16x8 a0 = *(const bf16x8*)sptr(Pb, wv * 32 + lr, 256, ks * 64 + lg * 16);
    bf16x8 a1 = *(const bf16x8*)sptr(Pb, wv * 32 + 16 + lr, 256, ks * 64 + lg * 16);
#pragma unroll
    for (int n = 0; n < 4; ++n) {
      bf16x8 b = *(const bf16x8*)sptr(Vb, n * 16 + lr, 256, ks * 64 + lg * 16);
      acco[0][n] = __builtin_amdgcn_mfma_f32_16x16x32_bf16(a0, b, acco[0][n], 0, 0, 0);
      acco[1][n] = __builtin_amdgcn_mfma_f32_16x16x32_bf16(a1, b, acco[1][n], 0, 0, 0);
    }
  }

  // ---------------- epilogue: LDS transpose -> float4 coalesced stores ----------------
  __syncthreads(); // P/V dead
  float* Ob = (float*)smem; // [120][68] f32
#pragma unroll
  for (int mt = 0; mt < 2; ++mt)
#pragma unroll
    for (int r = 0; r < 4; ++r) {
      int row = wv * 32 + mt * 16 + lg * 4 + r;
      if (row < CC) {
#pragma unroll
        for (int n = 0; n < 4; ++n)
          Ob[row * 68 + n * 16 + lr] = acco[mt][n][r];
      }
    }
  __syncthreads();
  const size_t obase = (size_t)batch * CC * HH;
#pragma unroll
  for (int i = 0; i < 8; ++i) {
    int idx = i * 256 + tid; // float4 index, 1920 total
    if (idx < 1920) {
      int row = idx >> 4;
      int c4 = (idx & 15) * 4;
      f32x4 v = *(const f32x4*)(Ob + row * 68 + c4);
      *(f32x4*)(out + obase + (size_t)idx * 4) = v;
    }
  }
}

extern "C" void kernel_launch(void* const* d_in, const int* in_sizes, int n_in,
                              void* d_out, int out_size, void* d_ws, size_t ws_size,
                              hipStream_t stream) {
  (void)in_sizes; (void)n_in; (void)out_size;
  const float* x  = (const float*)d_in[0];
  const float* Wk = (const float*)d_in[1];
  const float* Wq = (const float*)d_in[2];
  const float* Wv = (const float*)d_in[3];
  float* out = (float*)d_out;
  if (ws_size >= (size_t)WIMG_BYTES && d_ws != nullptr) {
    ushort_t* wimg = (ushort_t*)d_ws;
    prep_w<<<480, 256, 0, stream>>>(Wk, Wq, Wv, wimg);
    fused_regional_head<true><<<NBATCH, 256, 0, stream>>>(x, Wk, Wq, Wv, wimg, out);
  } else {
    fused_regional_head<false><<<NBATCH, 256, 0, stream>>>(x, Wk, Wq, Wv, nullptr, out);
  }
}

// Round 15
// 69.497 us; speedup vs baseline: 1.6063x; 1.6063x over previous
//
#include <hip/hip_runtime.h>
#include <hip/hip_bf16.h>

typedef __attribute__((ext_vector_type(8))) short bf16x8;
typedef __attribute__((ext_vector_type(4))) float f32x4;
typedef float f32x4u __attribute__((ext_vector_type(4), aligned(4))); // x rows only 4B-aligned
typedef __attribute__((ext_vector_type(4))) short short4v;
typedef unsigned short ushort_t;

#define CC 120
#define LL 469
#define HH 64

constexpr int NBATCH = 1024;
constexpr int KSTEPS = 15;

// ---- LDS layout ----
// phase 1: Wl[3][8192 shorts] = 49152 B (TRIPLE buffer; 15 live 1KB chunks + 1 pad each).
//          X in registers only. One barrier/region; W written 2 regions ahead of its read
//          -> provably race-free (writes issued after the barrier that retired all reads).
// phase 2: Qb @0 (16 KB, [128]x128B swz), Kb @16384, Vb @32768 ([64]x256B swz)
//          Pb @0 (32 KB) aliases Q+K after QK^T barrier; epilogue Ob f32 [120][68] @0
constexpr int WB_SHORTS   = 8192;                  // 16 KB per W buffer (padded)
constexpr int SMEM_BYTES  = 49152;                 // = 3 W buffers = phase2 footprint
constexpr int WIMG_SHORTS = KSTEPS * WB_SHORTS;    // 122880
constexpr int WIMG_BYTES  = WIMG_SHORTS * 2;       // 245760

__device__ __forceinline__ ushort_t f2bf(float f) {
  __hip_bfloat16 h = __float2bfloat16(f);
  return __builtin_bit_cast(ushort_t, h);
}

__device__ __forceinline__ void gload_lds16(const void* g, void* l) {
  __builtin_amdgcn_global_load_lds(
      (const __attribute__((address_space(1))) unsigned int*)g,
      (__attribute__((address_space(3))) unsigned int*)l, 16, 0, 0);
}

// XOR-swizzled LDS address for phase-2 tiles
__device__ __forceinline__ char* sptr(char* base, int row, int stride, int byteoff) {
  return base + row * stride + (byteoff ^ ((row & 7) << 4));
}

// W image: per step t a 16 KB block; first 15360 B = [192 cols][40 k] bf16, rest pad.
// Step 14 uses a SHIFTED window k = 437+kk with kk<11 zeroed (k=437..447 already
// covered by step 13) -> X step-14 vector loads are in-bounds and uniform.
__global__ void prep_w(const float* __restrict__ Wk, const float* __restrict__ Wq,
                       const float* __restrict__ Wv, ushort_t* __restrict__ wimg) {
  int idx = blockIdx.x * 256 + threadIdx.x; // 122880 exactly (480 blocks)
  int t = idx / WB_SHORTS;
  int r = idx % WB_SHORTS;
  int col = r / 40, kk = r % 40;
  float v = 0.f;
  if (r < 192 * 40 && kk < 32) {
    int kb = (t == 14) ? 437 : t * 32;
    int k = kb + kk;
    bool live = (k < LL) && (t < 14 || k >= 448);
    if (live) {
      int wsel = col >> 6, h = col & 63;
      const float* wp = (wsel == 0) ? Wk : (wsel == 1) ? Wq : Wv;
      v = wp[(size_t)k * HH + h];
    }
  }
  wimg[idx] = f2bf(v);
}

// X A-fragment loads: 4 vector loads into NAMED registers (never address-taken).
#define XISSUE(T, X0, X1, X2, X3)                                              \
  {                                                                            \
    const int _k = (((T) == 14) ? 437 : (T) * 32) + lg * 8;                    \
    X0 = *(const f32x4u*)(xr0 + _k);                                           \
    X1 = *(const f32x4u*)(xr0 + _k + 4);                                       \
    X2 = *(const f32x4u*)(xr1c + _k);                                          \
    X3 = *(const f32x4u*)(xr1c + _k + 4);                                      \
  }
// W stage into buffer (T)%3: exactly 4 global_load_lds16 per thread
#define WISSUE(T)                                                              \
  {                                                                            \
    const char* _src = (const char*)(wimg + (size_t)(T) * WB_SHORTS);          \
    char* _dst = (char*)(Wl + ((T) % 3) * WB_SHORTS);                          \
    _Pragma("unroll")                                                          \
    for (int _i = 0; _i < 4; ++_i) {                                           \
      int _c = wv + 4 * _i;                                                    \
      gload_lds16(_src + _c * 1024 + lane * 16, _dst + _c * 1024);             \
    }                                                                          \
  }
#define ENDREGION(N)                                                           \
  {                                                                            \
    __builtin_amdgcn_sched_barrier(0);                                         \
    asm volatile("s_waitcnt vmcnt(" #N ")" ::: "memory");                      \
    __builtin_amdgcn_sched_barrier(0);                                         \
    __builtin_amdgcn_s_barrier();                                              \
    __builtin_amdgcn_sched_barrier(0);                                         \
  }
#define COMPUTE(T, X0, X1, X2, X3)                                             \
  {                                                                            \
    const ushort_t* _wb = Wl + ((T) % 3) * WB_SHORTS;                          \
    bf16x8 _a0, _a1;                                                           \
    _Pragma("unroll")                                                          \
    for (int _j = 0; _j < 4; ++_j) {                                           \
      _a0[_j] = (short)f2bf(X0[_j]); _a0[4 + _j] = (short)f2bf(X1[_j]);        \
      _a1[_j] = (short)f2bf(X2[_j]); _a1[4 + _j] = (short)f2bf(X3[_j]);        \
    }                                                                          \
    _Pragma("unroll")                                                          \
    for (int _n = 0; _n < 12; ++_n) {                                          \
      bf16x8 _b = *(const bf16x8*)(_wb + (_n * 16 + lr) * 40 + lg * 8);        \
      acc[0][_n] = __builtin_amdgcn_mfma_f32_16x16x32_bf16(_a0, _b, acc[0][_n], 0, 0, 0); \
      acc[1][_n] = __builtin_amdgcn_mfma_f32_16x16x32_bf16(_a1, _b, acc[1][_n], 0, 0, 0); \
    }                                                                          \
  }

template <bool WIMG>
__global__ __launch_bounds__(256, 3)
void fused_regional_head(const float* __restrict__ x,
                         const float* __restrict__ Wk,
                         const float* __restrict__ Wq,
                         const float* __restrict__ Wv,
                         const ushort_t* __restrict__ wimg,
                         float* __restrict__ out) {
  __shared__ char smem[SMEM_BYTES];
  const int tid = threadIdx.x;
  const int lane = tid & 63;
  const int wv = tid >> 6;   // wave 0..3, owns rows 32*wv .. 32*wv+31
  const int lr = lane & 15;
  const int lg = lane >> 4;
  const int batch = blockIdx.x;
  const size_t xbase = (size_t)batch * CC * LL;

  ushort_t* Wl = (ushort_t*)smem; // [3][8192] shorts (phase 1 only)

  const int row0 = wv * 32 + lr;                    // < 120 always
  const int row1 = wv * 32 + 16 + lr;               // 120..127 for wave3 lr>=8
  const int row1c = (row1 < CC) ? row1 : (CC - 1);  // clamp: garbage masked downstream
  const float* xr0  = x + xbase + (size_t)row0 * LL;
  const float* xr1c = x + xbase + (size_t)row1c * LL;

  // ---------------- phase 1: QKV = X @ [Wk|Wq|Wv] ----------------
  f32x4 acc[2][12];
#pragma unroll
  for (int m = 0; m < 2; ++m)
#pragma unroll
    for (int n = 0; n < 12; ++n) acc[m][n] = (f32x4){0.f, 0.f, 0.f, 0.f};

  if constexpr (WIMG) {
    f32x4u xA0, xA1, xA2, xA3, xB0, xB1, xB2, xB3;
    // prologue: W(0),W(1) + X(0); full drain once
    WISSUE(0);
    WISSUE(1);
    XISSUE(0, xA0, xA1, xA2, xA3);
    ENDREGION(0);
    // regions 0..11 (pairs); region t: WISSUE(t+2) [buf free since barrier], XISSUE(t+1),
    // COMPUTE(t), vmcnt(8) -> everything older than this region's 8 retired.
#pragma unroll
    for (int tt = 0; tt < 6; ++tt) {
      const int t = 2 * tt;
      WISSUE(t + 2);
      XISSUE(t + 1, xB0, xB1, xB2, xB3);
      COMPUTE(t, xA0, xA1, xA2, xA3);
      ENDREGION(8);
      WISSUE(t + 3);
      XISSUE(t + 2, xA0, xA1, xA2, xA3);
      COMPUTE(t + 1, xB0, xB1, xB2, xB3);
      ENDREGION(8);
    }
    // region 12
    WISSUE(14);
    XISSUE(13, xB0, xB1, xB2, xB3);
    COMPUTE(12, xA0, xA1, xA2, xA3);
    ENDREGION(8);
    // region 13 (no W issue)
    XISSUE(14, xA0, xA1, xA2, xA3);
    COMPUTE(13, xB0, xB1, xB2, xB3);
    ENDREGION(0);
    // region 14
    COMPUTE(14, xA0, xA1, xA2, xA3);
  } else {
    // slow fallback (unused when ws present): unpipelined, W frags inline
    for (int t = 0; t < KSTEPS; ++t) {
      const int kb = (t == 14) ? 437 : t * 32;
      f32x4u x0 = *(const f32x4u*)(xr0 + kb + lg * 8);
      f32x4u x1 = *(const f32x4u*)(xr0 + kb + lg * 8 + 4);
      f32x4u x2 = *(const f32x4u*)(xr1c + kb + lg * 8);
      f32x4u x3 = *(const f32x4u*)(xr1c + kb + lg * 8 + 4);
      bf16x8 a0, a1;
#pragma unroll
      for (int j = 0; j < 4; ++j) {
        a0[j] = (short)f2bf(x0[j]); a0[4 + j] = (short)f2bf(x1[j]);
        a1[j] = (short)f2bf(x2[j]); a1[4 + j] = (short)f2bf(x3[j]);
      }
#pragma unroll
      for (int n = 0; n < 12; ++n) {
        int col = n * 16 + lr;
        int wsel = col >> 6, h = col & 63;
        const float* wp = (wsel == 0) ? Wk : (wsel == 1) ? Wq : Wv;
        bf16x8 b;
#pragma unroll
        for (int j = 0; j < 8; ++j) {
          int k = kb + lg * 8 + j;
          bool live = (k < LL) && (t < 14 || k >= 448);
          b[j] = (short)f2bf(live ? wp[(size_t)k * HH + h] : 0.f);
        }
        acc[0][n] = __builtin_amdgcn_mfma_f32_16x16x32_bf16(a0, b, acc[0][n], 0, 0, 0);
        acc[1][n] = __builtin_amdgcn_mfma_f32_16x16x32_bf16(a1, b, acc[1][n], 0, 0, 0);
      }
    }
  }
  __syncthreads(); // W region dead; phase-2 tiles take over

  // ---------------- write Q,K,V (bf16, swizzled) ----------------
  char* Qb = smem;
  char* Kb = smem + 16384;
  char* Vb = smem + 32768;
  char* Pb = smem;
#pragma unroll
  for (int mt = 0; mt < 2; ++mt) {
#pragma unroll
    for (int r = 0; r < 4; ++r) {
      int row = wv * 32 + mt * 16 + lg * 4 + r;
#pragma unroll
      for (int n = 0; n < 4; ++n) {
        *(ushort_t*)sptr(Kb, row, 128, (n * 16 + lr) * 2) = f2bf(acc[mt][n][r]);
        *(ushort_t*)sptr(Qb, row, 128, (n * 16 + lr) * 2) = f2bf(acc[mt][4 + n][r]);
      }
    }
    // V^T packed: 4 consecutive d-rows -> ds_write_b64
#pragma unroll
    for (int n = 0; n < 4; ++n) {
      short4v pk;
#pragma unroll
      for (int r = 0; r < 4; ++r) pk[r] = (short)f2bf(acc[mt][8 + n][r]);
      *(short4v*)sptr(Vb, n * 16 + lr, 256, (wv * 32 + mt * 16 + lg * 4) * 2) = pk;
    }
  }
  __syncthreads();

  // ---------------- QK^T ----------------
  f32x4 accw[2][8];
#pragma unroll
  for (int m = 0; m < 2; ++m)
#pragma unroll
    for (int n = 0; n < 8; ++n) accw[m][n] = (f32x4){0.f, 0.f, 0.f, 0.f};
#pragma unroll
  for (int ks = 0; ks < 2; ++ks) {
    bf16x8 a0 = *(const bf16x8*)sptr(Qb, wv * 32 + lr, 128, ks * 64 + lg * 16);
    bf16x8 a1 = *(const bf16x8*)sptr(Qb, wv * 32 + 16 + lr, 128, ks * 64 + lg * 16);
#pragma unroll
    for (int n = 0; n < 8; ++n) {
      bf16x8 b = *(const bf16x8*)sptr(Kb, n * 16 + lr, 128, ks * 64 + lg * 16);
      accw[0][n] = __builtin_amdgcn_mfma_f32_16x16x32_bf16(a0, b, accw[0][n], 0, 0, 0);
      accw[1][n] = __builtin_amdgcn_mfma_f32_16x16x32_bf16(a1, b, accw[1][n], 0, 0, 0);
    }
  }
  __syncthreads(); // all done reading Q/K before P overwrites

  // ---------------- softmax (wave-parallel over 16-lane col groups) ----------------
#pragma unroll
  for (int mt = 0; mt < 2; ++mt)
#pragma unroll
    for (int r = 0; r < 4; ++r) {
      float l[8];
      float m = -1e30f;
#pragma unroll
      for (int n = 0; n < 8; ++n) {
        float v = accw[mt][n][r] * 0.125f;
        if (n == 7 && lr >= 8) v = -1e30f; // col = 112+lr >= 120 masked
        l[n] = v;
        m = fmaxf(m, v);
      }
#pragma unroll
      for (int off = 1; off < 16; off <<= 1) m = fmaxf(m, __shfl_xor(m, off));
      float s = 0.f;
#pragma unroll
      for (int n = 0; n < 8; ++n) {
        float p = __expf(l[n] - m);
        l[n] = p;
        s += p;
      }
#pragma unroll
      for (int off = 1; off < 16; off <<= 1) s += __shfl_xor(s, off);
      float inv = 1.f / s;
      int row = wv * 32 + mt * 16 + lg * 4 + r;
#pragma unroll
      for (int n = 0; n < 8; ++n)
        *(ushort_t*)sptr(Pb, row, 256, (n * 16 + lr) * 2) = f2bf(l[n] * inv);
    }
  // no barrier: each wave reads only its own P rows; V covered by barrier above

  // ---------------- out = P @ V ----------------
  f32x4 acco[2][4];
#pragma unroll
  for (int m = 0; m < 2; ++m)
#pragma unroll
    for (int n = 0; n < 4; ++n) acco[m][n] = (f32x4){0.f, 0.f, 0.f, 0.f};
#pragma unroll
  for (int ks = 0; ks < 4; ++ks) {
    bf16x8 a0 = *(const bf16x8*)sptr(Pb, wv * 32 + lr, 256, ks * 64 + lg * 16);
    bf16x8 a1 = *(const bf16x8*)sptr(Pb, wv * 32 + 16 + lr, 256, ks * 64 + lg * 16);
#pragma unroll
    for (int n = 0; n < 4; ++n) {
      bf16x8 b = *(const bf16x8*)sptr(Vb, n * 16 + lr, 256, ks * 64 + lg * 16);
      acco[0][n] = __builtin_amdgcn_mfma_f32_16x16x32_bf16(a0, b, acco[0][n], 0, 0, 0);
      acco[1][n] = __builtin_amdgcn_mfma_f32_16x16x32_bf16(a1, b, acco[1][n], 0, 0, 0);
    }
  }

  // ---------------- epilogue: LDS transpose -> float4 coalesced stores ----------------
  __syncthreads(); // P/V dead
  float* Ob = (float*)smem; // [120][68] f32
#pragma unroll
  for (int mt = 0; mt < 2; ++mt)
#pragma unroll
    for (int r = 0; r < 4; ++r) {
      int row = wv * 32 + mt * 16 + lg * 4 + r;
      if (row < CC) {
#pragma unroll
        for (int n = 0; n < 4; ++n)
          Ob[row * 68 + n * 16 + lr] = acco[mt][n][r];
      }
    }
  __syncthreads();
  const size_t obase = (size_t)batch * CC * HH;
#pragma unroll
  for (int i = 0; i < 8; ++i) {
    int idx = i * 256 + tid; // float4 index, 1920 total
    if (idx < 1920) {
      int row = idx >> 4;
      int c4 = (idx & 15) * 4;
      f32x4 v = *(const f32x4*)(Ob + row * 68 + c4);
      *(f32x4*)(out + obase + (size_t)idx * 4) = v;
    }
  }
}

extern "C" void kernel_launch(void* const* d_in, const int* in_sizes, int n_in,
                              void* d_out, int out_size, void* d_ws, size_t ws_size,
                              hipStream_t stream) {
  (void)in_sizes; (void)n_in; (void)out_size;
  const float* x  = (const float*)d_in[0];
  const float* Wk = (const float*)d_in[1];
  const float* Wq = (const float*)d_in[2];
  const float* Wv = (const float*)d_in[3];
  float* out = (float*)d_out;
  if (ws_size >= (size_t)WIMG_BYTES && d_ws != nullptr) {
    ushort_t* wimg = (ushort_t*)d_ws;
    prep_w<<<480, 256, 0, stream>>>(Wk, Wq, Wv, wimg);
    fused_regional_head<true><<<NBATCH, 256, 0, stream>>>(x, Wk, Wq, Wv, wimg, out);
  } else {
    fused_regional_head<false><<<NBATCH, 256, 0, stream>>>(x, Wk, Wq, Wv, nullptr, out);
  }
}

// Round 16
// 68.237 us; speedup vs baseline: 1.6360x; 1.0185x over previous
//
#include <hip/hip_runtime.h>
#include <hip/hip_bf16.h>

typedef __attribute__((ext_vector_type(8))) short bf16x8;
typedef __attribute__((ext_vector_type(4))) float f32x4;
typedef float f32x4u __attribute__((ext_vector_type(4), aligned(4))); // x rows only 4B-aligned
typedef __attribute__((ext_vector_type(4))) short short4v;
typedef unsigned short ushort_t;

#define CC 120
#define LL 469
#define HH 64

constexpr int NBATCH = 1024;
constexpr int KSTEPS = 15;

// ---- LDS layout ----
// phase 1: Wl[3][8192 shorts] = 49152 B (triple buffer). X in registers (3 named sets).
//          DEPTH-2 pipeline: region t issues S(t+2) = {4 X loads, 4 W gload_lds};
//          end-of-region vmcnt(8) leaves exactly S(t+2) in flight -> S(t+1) landed.
//          Every load gets ~2 regions (>= HBM latency) of cover.
//          Race invariant (r15-proven): buf (t+2)%3 written in region t; its last
//          readers ran in region t-1, retired before the barrier -> no LDS race.
// phase 2: Qb @0 (16 KB, [128]x128B swz), Kb @16384, Vb @32768 ([64]x256B swz)
//          Pb @0 (32 KB) aliases Q+K after QK^T barrier; epilogue Ob f32 [120][68] @0
constexpr int WB_SHORTS   = 8192;                  // 16 KB per W buffer (padded)
constexpr int SMEM_BYTES  = 49152;                 // = 3 W buffers = phase2 footprint
constexpr int WIMG_SHORTS = KSTEPS * WB_SHORTS;    // 122880
constexpr int WIMG_BYTES  = WIMG_SHORTS * 2;       // 245760

__device__ __forceinline__ ushort_t f2bf(float f) {
  __hip_bfloat16 h = __float2bfloat16(f);
  return __builtin_bit_cast(ushort_t, h);
}

__device__ __forceinline__ void gload_lds16(const void* g, void* l) {
  __builtin_amdgcn_global_load_lds(
      (const __attribute__((address_space(1))) unsigned int*)g,
      (__attribute__((address_space(3))) unsigned int*)l, 16, 0, 0);
}

// XOR-swizzled LDS address for phase-2 tiles
__device__ __forceinline__ char* sptr(char* base, int row, int stride, int byteoff) {
  return base + row * stride + (byteoff ^ ((row & 7) << 4));
}

// W image: per step t a 16 KB block; first 15360 B = [192 cols][40 k] bf16, rest pad.
// Step 14 uses a SHIFTED window k = 437+kk with kk<11 zeroed (k=437..447 already
// covered by step 13) -> X step-14 vector loads are in-bounds and uniform.
__global__ void prep_w(const float* __restrict__ Wk, const float* __restrict__ Wq,
                       const float* __restrict__ Wv, ushort_t* __restrict__ wimg) {
  int idx = blockIdx.x * 256 + threadIdx.x; // 122880 exactly (480 blocks)
  int t = idx / WB_SHORTS;
  int r = idx % WB_SHORTS;
  int col = r / 40, kk = r % 40;
  float v = 0.f;
  if (r < 192 * 40 && kk < 32) {
    int kb = (t == 14) ? 437 : t * 32;
    int k = kb + kk;
    bool live = (k < LL) && (t < 14 || k >= 448);
    if (live) {
      int wsel = col >> 6, h = col & 63;
      const float* wp = (wsel == 0) ? Wk : (wsel == 1) ? Wq : Wv;
      v = wp[(size_t)k * HH + h];
    }
  }
  wimg[idx] = f2bf(v);
}

// X A-fragment loads: 4 vector loads into NAMED registers (never address-taken).
#define XISSUE(T, X0, X1, X2, X3)                                              \
  {                                                                            \
    const int _k = (((T) == 14) ? 437 : (T) * 32) + lg * 8;                    \
    X0 = *(const f32x4u*)(xr0 + _k);                                           \
    X1 = *(const f32x4u*)(xr0 + _k + 4);                                       \
    X2 = *(const f32x4u*)(xr1c + _k);                                          \
    X3 = *(const f32x4u*)(xr1c + _k + 4);                                      \
  }
// W stage into buffer (T)%3: exactly 4 global_load_lds16 per thread
#define WISSUE(T)                                                              \
  {                                                                            \
    const char* _src = (const char*)(wimg + (size_t)(T) * WB_SHORTS);          \
    char* _dst = (char*)(Wl + ((T) % 3) * WB_SHORTS);                          \
    _Pragma("unroll")                                                          \
    for (int _i = 0; _i < 4; ++_i) {                                           \
      int _c = wv + 4 * _i;                                                    \
      gload_lds16(_src + _c * 1024 + lane * 16, _dst + _c * 1024);             \
    }                                                                          \
  }
#define ENDREGION(N)                                                           \
  {                                                                            \
    __builtin_amdgcn_sched_barrier(0);                                         \
    asm volatile("s_waitcnt vmcnt(" #N ")" ::: "memory");                      \
    __builtin_amdgcn_sched_barrier(0);                                         \
    __builtin_amdgcn_s_barrier();                                              \
    __builtin_amdgcn_sched_barrier(0);                                         \
  }
#define COMPUTE(T, X0, X1, X2, X3)                                             \
  {                                                                            \
    const ushort_t* _wb = Wl + ((T) % 3) * WB_SHORTS;                          \
    bf16x8 _a0, _a1;                                                           \
    _Pragma("unroll")                                                          \
    for (int _j = 0; _j < 4; ++_j) {                                           \
      _a0[_j] = (short)f2bf(X0[_j]); _a0[4 + _j] = (short)f2bf(X1[_j]);        \
      _a1[_j] = (short)f2bf(X2[_j]); _a1[4 + _j] = (short)f2bf(X3[_j]);        \
    }                                                                          \
    _Pragma("unroll")                                                          \
    for (int _n = 0; _n < 12; ++_n) {                                          \
      bf16x8 _b = *(const bf16x8*)(_wb + (_n * 16 + lr) * 40 + lg * 8);        \
      acc[0][_n] = __builtin_amdgcn_mfma_f32_16x16x32_bf16(_a0, _b, acc[0][_n], 0, 0, 0); \
      acc[1][_n] = __builtin_amdgcn_mfma_f32_16x16x32_bf16(_a1, _b, acc[1][_n], 0, 0, 0); \
    }                                                                          \
  }

template <bool WIMG>
__global__ __launch_bounds__(256, 2)
void fused_regional_head(const float* __restrict__ x,
                         const float* __restrict__ Wk,
                         const float* __restrict__ Wq,
                         const float* __restrict__ Wv,
                         const ushort_t* __restrict__ wimg,
                         float* __restrict__ out) {
  __shared__ char smem[SMEM_BYTES];
  const int tid = threadIdx.x;
  const int lane = tid & 63;
  const int wv = tid >> 6;   // wave 0..3, owns rows 32*wv .. 32*wv+31
  const int lr = lane & 15;
  const int lg = lane >> 4;
  const int batch = blockIdx.x;
  const size_t xbase = (size_t)batch * CC * LL;

  ushort_t* Wl = (ushort_t*)smem; // [3][8192] shorts (phase 1 only)

  const int row0 = wv * 32 + lr;                    // < 120 always
  const int row1 = wv * 32 + 16 + lr;               // 120..127 for wave3 lr>=8
  const int row1c = (row1 < CC) ? row1 : (CC - 1);  // clamp: garbage masked downstream
  const float* xr0  = x + xbase + (size_t)row0 * LL;
  const float* xr1c = x + xbase + (size_t)row1c * LL;

  // ---------------- phase 1: QKV = X @ [Wk|Wq|Wv], depth-2 pipeline ----------------
  f32x4 acc[2][12];
#pragma unroll
  for (int m = 0; m < 2; ++m)
#pragma unroll
    for (int n = 0; n < 12; ++n) acc[m][n] = (f32x4){0.f, 0.f, 0.f, 0.f};

  if constexpr (WIMG) {
    // 3 named X register sets (A=t%3==0, B==1, C==2)
    f32x4u xA0, xA1, xA2, xA3, xB0, xB1, xB2, xB3, xC0, xC1, xC2, xC3;
    // prologue: S(0), S(1) in flight; drain S(0) only
    WISSUE(0);
    XISSUE(0, xA0, xA1, xA2, xA3);
    WISSUE(1);
    XISSUE(1, xB0, xB1, xB2, xB3);
    ENDREGION(8);
    // regions 0..11: region t issues S(t+2), computes t, drains S(t+1)
#pragma unroll
    for (int tt = 0; tt < 4; ++tt) {
      const int t = 3 * tt;
      WISSUE(t + 2); XISSUE(t + 2, xC0, xC1, xC2, xC3);
      COMPUTE(t, xA0, xA1, xA2, xA3);
      ENDREGION(8);
      WISSUE(t + 3); XISSUE(t + 3, xA0, xA1, xA2, xA3);
      COMPUTE(t + 1, xB0, xB1, xB2, xB3);
      ENDREGION(8);
      WISSUE(t + 4); XISSUE(t + 4, xB0, xB1, xB2, xB3);
      COMPUTE(t + 2, xC0, xC1, xC2, xC3);
      ENDREGION(8);
    }
    // region 12: issue S(14), compute 12
    WISSUE(14); XISSUE(14, xC0, xC1, xC2, xC3);
    COMPUTE(12, xA0, xA1, xA2, xA3);
    ENDREGION(8);
    // region 13: no issue; compute 13; drain everything
    COMPUTE(13, xB0, xB1, xB2, xB3);
    ENDREGION(0);
    // region 14
    COMPUTE(14, xC0, xC1, xC2, xC3);
  } else {
    // slow fallback (unused when ws present): unpipelined, W frags inline
    for (int t = 0; t < KSTEPS; ++t) {
      const int kb = (t == 14) ? 437 : t * 32;
      f32x4u x0 = *(const f32x4u*)(xr0 + kb + lg * 8);
      f32x4u x1 = *(const f32x4u*)(xr0 + kb + lg * 8 + 4);
      f32x4u x2 = *(const f32x4u*)(xr1c + kb + lg * 8);
      f32x4u x3 = *(const f32x4u*)(xr1c + kb + lg * 8 + 4);
      bf16x8 a0, a1;
#pragma unroll
      for (int j = 0; j < 4; ++j) {
        a0[j] = (short)f2bf(x0[j]); a0[4 + j] = (short)f2bf(x1[j]);
        a1[j] = (short)f2bf(x2[j]); a1[4 + j] = (short)f2bf(x3[j]);
      }
#pragma unroll
      for (int n = 0; n < 12; ++n) {
        int col = n * 16 + lr;
        int wsel = col >> 6, h = col & 63;
        const float* wp = (wsel == 0) ? Wk : (wsel == 1) ? Wq : Wv;
        bf16x8 b;
#pragma unroll
        for (int j = 0; j < 8; ++j) {
          int k = kb + lg * 8 + j;
          bool live = (k < LL) && (t < 14 || k >= 448);
          b[j] = (short)f2bf(live ? wp[(size_t)k * HH + h] : 0.f);
        }
        acc[0][n] = __builtin_amdgcn_mfma_f32_16x16x32_bf16(a0, b, acc[0][n], 0, 0, 0);
        acc[1][n] = __builtin_amdgcn_mfma_f32_16x16x32_bf16(a1, b, acc[1][n], 0, 0, 0);
      }
    }
  }
  __syncthreads(); // W region dead; phase-2 tiles take over

  // ---------------- write Q,K,V (bf16, swizzled) ----------------
  char* Qb = smem;
  char* Kb = smem + 16384;
  char* Vb = smem + 32768;
  char* Pb = smem;
#pragma unroll
  for (int mt = 0; mt < 2; ++mt) {
#pragma unroll
    for (int r = 0; r < 4; ++r) {
      int row = wv * 32 + mt * 16 + lg * 4 + r;
#pragma unroll
      for (int n = 0; n < 4; ++n) {
        *(ushort_t*)sptr(Kb, row, 128, (n * 16 + lr) * 2) = f2bf(acc[mt][n][r]);
        *(ushort_t*)sptr(Qb, row, 128, (n * 16 + lr) * 2) = f2bf(acc[mt][4 + n][r]);
      }
    }
    // V^T packed: 4 consecutive d-rows -> ds_write_b64
#pragma unroll
    for (int n = 0; n < 4; ++n) {
      short4v pk;
#pragma unroll
      for (int r = 0; r < 4; ++r) pk[r] = (short)f2bf(acc[mt][8 + n][r]);
      *(short4v*)sptr(Vb, n * 16 + lr, 256, (wv * 32 + mt * 16 + lg * 4) * 2) = pk;
    }
  }
  __syncthreads();

  // ---------------- QK^T ----------------
  f32x4 accw[2][8];
#pragma unroll
  for (int m = 0; m < 2; ++m)
#pragma unroll
    for (int n = 0; n < 8; ++n) accw[m][n] = (f32x4){0.f, 0.f, 0.f, 0.f};
#pragma unroll
  for (int ks = 0; ks < 2; ++ks) {
    bf16x8 a0 = *(const bf16x8*)sptr(Qb, wv * 32 + lr, 128, ks * 64 + lg * 16);
    bf16x8 a1 = *(const bf16x8*)sptr(Qb, wv * 32 + 16 + lr, 128, ks * 64 + lg * 16);
#pragma unroll
    for (int n = 0; n < 8; ++n) {
      bf16x8 b = *(const bf16x8*)sptr(Kb, n * 16 + lr, 128, ks * 64 + lg * 16);
      accw[0][n] = __builtin_amdgcn_mfma_f32_16x16x32_bf16(a0, b, accw[0][n], 0, 0, 0);
      accw[1][n] = __builtin_amdgcn_mfma_f32_16x16x32_bf16(a1, b, accw[1][n], 0, 0, 0);
    }
  }
  __syncthreads(); // all done reading Q/K before P overwrites

  // ---------------- softmax (wave-parallel over 16-lane col groups) ----------------
#pragma unroll
  for (int mt = 0; mt < 2; ++mt)
#pragma unroll
    for (int r = 0; r < 4; ++r) {
      float l[8];
      float m = -1e30f;
#pragma unroll
      for (int n = 0; n < 8; ++n) {
        float v = accw[mt][n][r] * 0.125f;
        if (n == 7 && lr >= 8) v = -1e30f; // col = 112+lr >= 120 masked
        l[n] = v;
        m = fmaxf(m, v);
      }
#pragma unroll
      for (int off = 1; off < 16; off <<= 1) m = fmaxf(m, __shfl_xor(m, off));
      float s = 0.f;
#pragma unroll
      for (int n = 0; n < 8; ++n) {
        float p = __expf(l[n] - m);
        l[n] = p;
        s += p;
      }
#pragma unroll
      for (int off = 1; off < 16; off <<= 1) s += __shfl_xor(s, off);
      float inv = 1.f / s;
      int row = wv * 32 + mt * 16 + lg * 4 + r;
#pragma unroll
      for (int n = 0; n < 8; ++n)
        *(ushort_t*)sptr(Pb, row, 256, (n * 16 + lr) * 2) = f2bf(l[n] * inv);
    }
  // no barrier: each wave reads only its own P rows; V covered by barrier above

  // ---------------- out = P @ V ----------------
  f32x4 acco[2][4];
#pragma unroll
  for (int m = 0; m < 2; ++m)
#pragma unroll
    for (int n = 0; n < 4; ++n) acco[m][n] = (f32x4){0.f, 0.f, 0.f, 0.f};
#pragma unroll
  for (int ks = 0; ks < 4; ++ks) {
    bf16x8 a0 = *(const bf16x8*)sptr(Pb, wv * 32 + lr, 256, ks * 64 + lg * 16);
    bf16x8 a1 = *(const bf16x8*)sptr(Pb, wv * 32 + 16 + lr, 256, ks * 64 + lg * 16);
#pragma unroll
    for (int n = 0; n < 4; ++n) {
      bf16x8 b = *(const bf16x8*)sptr(Vb, n * 16 + lr, 256, ks * 64 + lg * 16);
      acco[0][n] = __builtin_amdgcn_mfma_f32_16x16x32_bf16(a0, b, acco[0][n], 0, 0, 0);
      acco[1][n] = __builtin_amdgcn_mfma_f32_16x16x32_bf16(a1, b, acco[1][n], 0, 0, 0);
    }
  }

  // ---------------- epilogue: LDS transpose -> float4 coalesced stores ----------------
  __syncthreads(); // P/V dead
  float* Ob = (float*)smem; // [120][68] f32
#pragma unroll
  for (int mt = 0; mt < 2; ++mt)
#pragma unroll
    for (int r = 0; r < 4; ++r) {
      int row = wv * 32 + mt * 16 + lg * 4 + r;
      if (row < CC) {
#pragma unroll
        for (int n = 0; n < 4; ++n)
          Ob[row * 68 + n * 16 + lr] = acco[mt][n][r];
      }
    }
  __syncthreads();
  const size_t obase = (size_t)batch * CC * HH;
#pragma unroll
  for (int i = 0; i < 8; ++i) {
    int idx = i * 256 + tid; // float4 index, 1920 total
    if (idx < 1920) {
      int row = idx >> 4;
      int c4 = (idx & 15) * 4;
      f32x4 v = *(const f32x4*)(Ob + row * 68 + c4);
      *(f32x4*)(out + obase + (size_t)idx * 4) = v;
    }
  }
}

extern "C" void kernel_launch(void* const* d_in, const int* in_sizes, int n_in,
                              void* d_out, int out_size, void* d_ws, size_t ws_size,
                              hipStream_t stream) {
  (void)in_sizes; (void)n_in; (void)out_size;
  const float* x  = (const float*)d_in[0];
  const float* Wk = (const float*)d_in[1];
  const float* Wq = (const float*)d_in[2];
  const float* Wv = (const float*)d_in[3];
  float* out = (float*)d_out;
  if (ws_size >= (size_t)WIMG_BYTES && d_ws != nullptr) {
    ushort_t* wimg = (ushort_t*)d_ws;
    prep_w<<<480, 256, 0, stream>>>(Wk, Wq, Wv, wimg);
    fused_regional_head<true><<<NBATCH, 256, 0, stream>>>(x, Wk, Wq, Wv, wimg, out);
  } else {
    fused_regional_head<false><<<NBATCH, 256, 0, stream>>>(x, Wk, Wq, Wv, nullptr, out);
  }
}